// Round 3
// baseline (47.240 us; speedup 1.0000x reference)
//
#include <hip/hip_runtime.h>

// Batched 4x4 symmetric eigenvalues via cyclic Jacobi (values only).
// One thread = one matrix. H diag = concat(E1,E2); strict upper = C in
// row-major pair order (0,1),(0,2),(0,3),(1,2),(1,3),(2,3).

__global__ __launch_bounds__(256) void eig4_jacobi_kernel(
    const float* __restrict__ E1,
    const float* __restrict__ E2,
    const float* __restrict__ C,
    float* __restrict__ out,
    int B)
{
    int i = blockIdx.x * blockDim.x + threadIdx.x;
    if (i >= B) return;

    // Coalesced vector loads: 8B-aligned for every i.
    float2 e1 = *reinterpret_cast<const float2*>(E1 + 2 * i);
    float2 e2 = *reinterpret_cast<const float2*>(E2 + 2 * i);
    const float2* c2 = reinterpret_cast<const float2*>(C + 6 * i);
    float2 ca = c2[0];
    float2 cb = c2[1];
    float2 cc = c2[2];

    // Full symmetric 4x4 in registers (constant indices only).
    float a[4][4];
    a[0][0] = e1.x; a[1][1] = e1.y; a[2][2] = e2.x; a[3][3] = e2.y;
    a[0][1] = a[1][0] = ca.x;   // (0,1)
    a[0][2] = a[2][0] = ca.y;   // (0,2)
    a[0][3] = a[3][0] = cb.x;   // (0,3)
    a[1][2] = a[2][1] = cb.y;   // (1,2)
    a[1][3] = a[3][1] = cc.x;   // (1,3)
    a[2][3] = a[3][2] = cc.y;   // (2,3)

    // One Jacobi rotation zeroing a[p][q]; r0,r1 are the other two rows.
    // Branchless: t = 2*apq*sign(h) / (|h| + sqrt(h^2 + 4*apq^2)), denom
    // clamped so apq==h==0 gives t=0 (identity rotation).
#define ROT(p, q, r0, r1)                                                   \
    {                                                                       \
        float apq = a[p][q];                                                \
        float h = a[q][q] - a[p][p];                                        \
        float denom = fabsf(h) + sqrtf(fmaf(h, h, 4.0f * apq * apq));       \
        float t = (2.0f * apq * copysignf(1.0f, h)) / fmaxf(denom, 1e-30f); \
        float c = rsqrtf(fmaf(t, t, 1.0f));                                 \
        float s = t * c;                                                    \
        a[p][p] = fmaf(-t, apq, a[p][p]);                                   \
        a[q][q] = fmaf(t, apq, a[q][q]);                                    \
        a[p][q] = 0.0f; a[q][p] = 0.0f;                                     \
        {                                                                   \
            float arp = a[r0][p], arq = a[r0][q];                           \
            a[r0][p] = a[p][r0] = fmaf(c, arp, -s * arq);                   \
            a[r0][q] = a[q][r0] = fmaf(s, arp, c * arq);                    \
        }                                                                   \
        {                                                                   \
            float arp = a[r1][p], arq = a[r1][q];                           \
            a[r1][p] = a[p][r1] = fmaf(c, arp, -s * arq);                   \
            a[r1][q] = a[q][r1] = fmaf(s, arp, c * arq);                    \
        }                                                                   \
    }

    // 5 cyclic sweeps: quadratic convergence -> ~1e-6 off-norm on 4x4,
    // far below the 0.156 acceptance threshold.
    #pragma unroll
    for (int sweep = 0; sweep < 5; ++sweep) {
        ROT(0, 1, 2, 3);
        ROT(0, 2, 1, 3);
        ROT(0, 3, 1, 2);
        ROT(1, 2, 0, 3);
        ROT(1, 3, 0, 2);
        ROT(2, 3, 0, 1);
    }
#undef ROT

    float w = a[0][0], x = a[1][1], y = a[2][2], z = a[3][3];

    // Ascending sort, 5-comparator network.
#define CSWAP(u, v) { float lo = fminf(u, v), hi = fmaxf(u, v); u = lo; v = hi; }
    CSWAP(w, x); CSWAP(y, z); CSWAP(w, y); CSWAP(x, z); CSWAP(x, y);
#undef CSWAP

    *reinterpret_cast<float4*>(out + 4 * i) = make_float4(w, x, y, z);
}

extern "C" void kernel_launch(void* const* d_in, const int* in_sizes, int n_in,
                              void* d_out, int out_size, void* d_ws, size_t ws_size,
                              hipStream_t stream)
{
    const float* E1 = (const float*)d_in[0];
    const float* E2 = (const float*)d_in[1];
    const float* C  = (const float*)d_in[2];
    float* out = (float*)d_out;

    int B = in_sizes[0] / 2;  // E1 is [B, 2]
    int block = 256;
    int grid = (B + block - 1) / block;
    eig4_jacobi_kernel<<<grid, block, 0, stream>>>(E1, E2, C, out, B);
}

// Round 4
// 29.795 us; speedup vs baseline: 1.5855x; 1.5855x over previous
//
#include <hip/hip_runtime.h>

// Batched 4x4 symmetric eigenvalues via cyclic Jacobi (values only).
// One thread = one matrix. H diag = concat(E1,E2); strict upper = C in
// row-major pair order (0,1),(0,2),(0,3),(1,2),(1,3),(2,3).
//
// R4: replace IEEE div/sqrt/rsqrt libcall expansions (~10/6/5 ops each)
// with raw gfx950 approximation instructions (v_rcp/v_sqrt/v_rsq, 1-2 ulp).
// Kernel is VALU-issue-bound (R3: VALUBusy 85%, HBM 9%), so issue-slot
// count is the lever.

__global__ __launch_bounds__(256) void eig4_jacobi_kernel(
    const float* __restrict__ E1,
    const float* __restrict__ E2,
    const float* __restrict__ C,
    float* __restrict__ out,
    int B)
{
    int i = blockIdx.x * blockDim.x + threadIdx.x;
    if (i >= B) return;

    // Coalesced vector loads: 8B-aligned for every i.
    float2 e1 = *reinterpret_cast<const float2*>(E1 + 2 * i);
    float2 e2 = *reinterpret_cast<const float2*>(E2 + 2 * i);
    const float2* c2 = reinterpret_cast<const float2*>(C + 6 * i);
    float2 ca = c2[0];
    float2 cb = c2[1];
    float2 cc = c2[2];

    // Full symmetric 4x4 in registers (constant indices only).
    float a[4][4];
    a[0][0] = e1.x; a[1][1] = e1.y; a[2][2] = e2.x; a[3][3] = e2.y;
    a[0][1] = a[1][0] = ca.x;   // (0,1)
    a[0][2] = a[2][0] = ca.y;   // (0,2)
    a[0][3] = a[3][0] = cb.x;   // (0,3)
    a[1][2] = a[2][1] = cb.y;   // (1,2)
    a[1][3] = a[3][1] = cc.x;   // (1,3)
    a[2][3] = a[3][2] = cc.y;   // (2,3)

    // One Jacobi rotation zeroing a[p][q]; r0,r1 are the other two rows.
    // t = 2*apq*sign(h) / (|h| + sqrt(h^2 + 4*apq^2)), denom clamped so
    // apq==h==0 gives t=0. u = 2*apq reused in fma(u,u,h*h) = h^2+4*apq^2.
    // v_rcp/v_sqrt/v_rsq are 1-2 ulp: negligible vs 0.156 threshold.
#define ROT(p, q, r0, r1)                                                   \
    {                                                                       \
        float apq = a[p][q];                                                \
        float h = a[q][q] - a[p][p];                                        \
        float u = apq + apq;                                                \
        float r = __builtin_amdgcn_sqrtf(fmaf(u, u, h * h));                \
        float denom = fmaxf(fabsf(h) + r, 1e-30f);                          \
        float t = u * copysignf(1.0f, h) * __builtin_amdgcn_rcpf(denom);    \
        float c = __builtin_amdgcn_rsqf(fmaf(t, t, 1.0f));                  \
        float s = t * c;                                                    \
        a[p][p] = fmaf(-t, apq, a[p][p]);                                   \
        a[q][q] = fmaf(t, apq, a[q][q]);                                    \
        a[p][q] = 0.0f; a[q][p] = 0.0f;                                     \
        {                                                                   \
            float arp = a[r0][p], arq = a[r0][q];                           \
            a[r0][p] = a[p][r0] = fmaf(c, arp, -s * arq);                   \
            a[r0][q] = a[q][r0] = fmaf(s, arp, c * arq);                    \
        }                                                                   \
        {                                                                   \
            float arp = a[r1][p], arq = a[r1][q];                           \
            a[r1][p] = a[p][r1] = fmaf(c, arp, -s * arq);                   \
            a[r1][q] = a[q][r1] = fmaf(s, arp, c * arq);                    \
        }                                                                   \
    }

    // 5 cyclic sweeps (R3 absmax 0.031 vs threshold 0.156).
    #pragma unroll
    for (int sweep = 0; sweep < 5; ++sweep) {
        ROT(0, 1, 2, 3);
        ROT(0, 2, 1, 3);
        ROT(0, 3, 1, 2);
        ROT(1, 2, 0, 3);
        ROT(1, 3, 0, 2);
        ROT(2, 3, 0, 1);
    }
#undef ROT

    float w = a[0][0], x = a[1][1], y = a[2][2], z = a[3][3];

    // Ascending sort, 5-comparator network.
#define CSWAP(u, v) { float lo = fminf(u, v), hi = fmaxf(u, v); u = lo; v = hi; }
    CSWAP(w, x); CSWAP(y, z); CSWAP(w, y); CSWAP(x, z); CSWAP(x, y);
#undef CSWAP

    *reinterpret_cast<float4*>(out + 4 * i) = make_float4(w, x, y, z);
}

extern "C" void kernel_launch(void* const* d_in, const int* in_sizes, int n_in,
                              void* d_out, int out_size, void* d_ws, size_t ws_size,
                              hipStream_t stream)
{
    const float* E1 = (const float*)d_in[0];
    const float* E2 = (const float*)d_in[1];
    const float* C  = (const float*)d_in[2];
    float* out = (float*)d_out;

    int B = in_sizes[0] / 2;  // E1 is [B, 2]
    int block = 256;
    int grid = (B + block - 1) / block;
    eig4_jacobi_kernel<<<grid, block, 0, stream>>>(E1, E2, C, out, B);
}

// Round 5
// 25.913 us; speedup vs baseline: 1.8230x; 1.1498x over previous
//
#include <hip/hip_runtime.h>

// Batched 4x4 symmetric eigenvalues via cyclic Jacobi (values only).
// One thread = one matrix. H diag = concat(E1,E2); strict upper = C in
// row-major pair order (0,1),(0,2),(0,3),(1,2),(1,3),(2,3).
//
// R4: v_rcp/v_sqrt/v_rsq approximation instrs (50->29.8us).
// R5: (a) fold sign/clamp: d = h + copysign(r+eps, h), t = u*rcp(d)
//     (b) __launch_bounds__(256,8): 8 waves/SIMD (R3 occupancy 58%)
//     (c) wave-uniform skip of sweep 5 when all 64 matrices converged.

__global__ __launch_bounds__(256, 8) void eig4_jacobi_kernel(
    const float* __restrict__ E1,
    const float* __restrict__ E2,
    const float* __restrict__ C,
    float* __restrict__ out,
    int B)
{
    int i = blockIdx.x * blockDim.x + threadIdx.x;
    if (i >= B) return;

    // Coalesced vector loads: 8B-aligned for every i.
    float2 e1 = *reinterpret_cast<const float2*>(E1 + 2 * i);
    float2 e2 = *reinterpret_cast<const float2*>(E2 + 2 * i);
    const float2* c2 = reinterpret_cast<const float2*>(C + 6 * i);
    float2 ca = c2[0];
    float2 cb = c2[1];
    float2 cc = c2[2];

    // Full symmetric 4x4 in registers (constant indices only).
    float a[4][4];
    a[0][0] = e1.x; a[1][1] = e1.y; a[2][2] = e2.x; a[3][3] = e2.y;
    a[0][1] = a[1][0] = ca.x;   // (0,1)
    a[0][2] = a[2][0] = ca.y;   // (0,2)
    a[0][3] = a[3][0] = cb.x;   // (0,3)
    a[1][2] = a[2][1] = cb.y;   // (1,2)
    a[1][3] = a[3][1] = cc.x;   // (1,3)
    a[2][3] = a[3][2] = cc.y;   // (2,3)

    // One Jacobi rotation zeroing a[p][q]; r0,r1 are the other two rows.
    // t = u / (h + copysign(r+eps, h)), u = 2*apq, r = sqrt(h^2+u^2).
    //   h>0: d =  (|h|+r) -> t = +u/(|h|+r);  h<0: d = -(|h|+r) -> -u/(..)
    //   h=0, apq!=0: t = sign(apq) (45-deg rotation, correct limit)
    //   h=0, apq=0:  t = 0 (identity). r >= |u| ensures |t| <= 1.
#define ROT(p, q, r0, r1)                                                   \
    {                                                                       \
        float apq = a[p][q];                                                \
        float h = a[q][q] - a[p][p];                                        \
        float u = apq + apq;                                                \
        float r = __builtin_amdgcn_sqrtf(fmaf(u, u, h * h)) + 1e-30f;       \
        float d = h + copysignf(r, h);                                      \
        float t = u * __builtin_amdgcn_rcpf(d);                             \
        float c = __builtin_amdgcn_rsqf(fmaf(t, t, 1.0f));                  \
        float s = t * c;                                                    \
        a[p][p] = fmaf(-t, apq, a[p][p]);                                   \
        a[q][q] = fmaf(t, apq, a[q][q]);                                    \
        a[p][q] = 0.0f; a[q][p] = 0.0f;                                     \
        {                                                                   \
            float arp = a[r0][p], arq = a[r0][q];                           \
            a[r0][p] = a[p][r0] = fmaf(c, arp, -s * arq);                   \
            a[r0][q] = a[q][r0] = fmaf(s, arp, c * arq);                    \
        }                                                                   \
        {                                                                   \
            float arp = a[r1][p], arq = a[r1][q];                           \
            a[r1][p] = a[p][r1] = fmaf(c, arp, -s * arq);                   \
            a[r1][q] = a[q][r1] = fmaf(s, arp, c * arq);                    \
        }                                                                   \
    }

#define SWEEP                                                               \
    ROT(0, 1, 2, 3);                                                        \
    ROT(0, 2, 1, 3);                                                        \
    ROT(0, 3, 1, 2);                                                        \
    ROT(1, 2, 0, 3);                                                        \
    ROT(1, 3, 0, 2);                                                        \
    ROT(2, 3, 0, 1);

    // 4 mandatory sweeps, then sweep 5 only if any lane's off-diagonal
    // norm^2 >= 1e-8 (lambda error ~1e-4 when skipped, vs 0.031 budget).
    // Wave-uniform branch: no divergence; converged lanes in a mixed wave
    // just do near-identity rotations.
    SWEEP; SWEEP; SWEEP; SWEEP;

    float off2 = a[0][1] * a[0][1];
    off2 = fmaf(a[0][2], a[0][2], off2);
    off2 = fmaf(a[0][3], a[0][3], off2);
    off2 = fmaf(a[1][2], a[1][2], off2);
    off2 = fmaf(a[1][3], a[1][3], off2);
    off2 = fmaf(a[2][3], a[2][3], off2);
    if (!__all(off2 < 1e-8f)) {
        SWEEP;
    }
#undef SWEEP
#undef ROT

    float w = a[0][0], x = a[1][1], y = a[2][2], z = a[3][3];

    // Ascending sort, 5-comparator network.
#define CSWAP(u, v) { float lo = fminf(u, v), hi = fmaxf(u, v); u = lo; v = hi; }
    CSWAP(w, x); CSWAP(y, z); CSWAP(w, y); CSWAP(x, z); CSWAP(x, y);
#undef CSWAP

    *reinterpret_cast<float4*>(out + 4 * i) = make_float4(w, x, y, z);
}

extern "C" void kernel_launch(void* const* d_in, const int* in_sizes, int n_in,
                              void* d_out, int out_size, void* d_ws, size_t ws_size,
                              hipStream_t stream)
{
    const float* E1 = (const float*)d_in[0];
    const float* E2 = (const float*)d_in[1];
    const float* C  = (const float*)d_in[2];
    float* out = (float*)d_out;

    int B = in_sizes[0] / 2;  // E1 is [B, 2]
    int block = 256;
    int grid = (B + block - 1) / block;
    eig4_jacobi_kernel<<<grid, block, 0, stream>>>(E1, E2, C, out, B);
}